// Round 7
// baseline (74.325 us; speedup 1.0000x reference)
//
#include <hip/hip_runtime.h>
#include <hip/hip_bf16.h>

typedef __bf16 bf16x8 __attribute__((ext_vector_type(8)));
typedef float  f32x4  __attribute__((ext_vector_type(4)));

// 256 threads = 4 waves; one output column-block c, 256 M-rows (64/wave).
// B (4 nonzero 64x64 blocks of column c) staged ONCE to LDS (bf16, [s][n][k]
// transposed, XOR-swizzled); A fragments loaded directly from global (fp32),
// converted in-register. Main loop: 16 steps (mt x s), depth-4 prefetch
// pf[4][4] (64 VGPRs live by construction) with sched_barrier(0) pinning the
// load-issue point each step — rounds 4/6 showed the compiler re-rolls the
// pipeline otherwise (VGPR 60/40, loads just-in-time, ~3 TB/s). One barrier.
// launch_bounds(256,4): VGPR cap 128 (round 5 proved an 8-wave/EU cap spills).
__global__ __launch_bounds__(256, 4) void sparse_linear_kernel(
    const float* __restrict__ A, const float* __restrict__ Bd,
    const int* __restrict__ rowi, const int* __restrict__ di,
    float* __restrict__ C)
{
    __shared__ __align__(16) unsigned short Bt[4 * 64 * 64];   // 32 KB
    char* BtB = (char*)Bt;

    const int bid = blockIdx.x;
    const int c   = bid & 63;          // m-chunk-major; sharers c,c+16,.. same XCD class
    const int mch = bid >> 6;          // 0..31
    const int t    = threadIdx.x;
    const int lane = t & 63;
    const int w    = t >> 6;           // 0..3

    int rs[4], ds[4];
    #pragma unroll
    for (int s = 0; s < 4; ++s) {
        rs[s] = rowi[s * 64 + c];
        ds[s] = di[s * 64 + c];
    }
    int koff[4];
    #pragma unroll
    for (int s = 0; s < 4; ++s) koff[s] = rs[s] * 64;

    const long mbase = (long)mch * 256 + w * 64;
    const float* Abase = A + (mbase + (lane & 15)) * 4096 + (lane >> 4) * 8;

    // ---- prologue: prefetch steps 0..3 (mt=0, s=0..3) -> 16 float4 in flight ----
    float4 pf[4][4];
    #pragma unroll
    for (int st = 0; st < 4; ++st) {
        const float* p = Abase + koff[st];
        pf[st][0] = *(const float4*)(p);
        pf[st][1] = *(const float4*)(p + 4);
        pf[st][2] = *(const float4*)(p + 32);
        pf[st][3] = *(const float4*)(p + 36);
    }

    // ---- stage B once: wave sb stages block sb; lane n owns column n ----
    {
        const int n  = t & 63;
        const int sb = t >> 6;
        const float* Bg = Bd + (long)ds[sb] * 64 + n;   // row stride = BN*TB = 16384
        char* dst = BtB + sb * 8192 + n * 128;
        const int sw = (n & 7) << 4;
        #pragma unroll
        for (int k4 = 0; k4 < 16; ++k4) {
            union { ushort4 u; __bf16 e[4]; } pk;
            pk.e[0] = (__bf16)Bg[(long)(4 * k4 + 0) * 16384];
            pk.e[1] = (__bf16)Bg[(long)(4 * k4 + 1) * 16384];
            pk.e[2] = (__bf16)Bg[(long)(4 * k4 + 2) * 16384];
            pk.e[3] = (__bf16)Bg[(long)(4 * k4 + 3) * 16384];
            *(ushort4*)(dst + ((8 * k4) ^ sw)) = pk.u;
        }
    }
    __syncthreads();   // the only barrier

    f32x4 acc[4];
    #pragma unroll
    for (int n2 = 0; n2 < 4; ++n2) acc[n2] = f32x4{0.f, 0.f, 0.f, 0.f};

    #pragma unroll
    for (int step = 0; step < 16; ++step) {
        const int mt = step >> 2, s = step & 3, slot = step & 3;

        // convert this step's A fragments (consumes pf[slot], freeing the slot)
        union { bf16x8 v; __bf16 e[8]; } af0, af1;
        {
            const float4 a0 = pf[slot][0], a1 = pf[slot][1];
            const float4 a2 = pf[slot][2], a3 = pf[slot][3];
            af0.e[0] = (__bf16)a0.x; af0.e[1] = (__bf16)a0.y;
            af0.e[2] = (__bf16)a0.z; af0.e[3] = (__bf16)a0.w;
            af0.e[4] = (__bf16)a1.x; af0.e[5] = (__bf16)a1.y;
            af0.e[6] = (__bf16)a1.z; af0.e[7] = (__bf16)a1.w;
            af1.e[0] = (__bf16)a2.x; af1.e[1] = (__bf16)a2.y;
            af1.e[2] = (__bf16)a2.z; af1.e[3] = (__bf16)a2.w;
            af1.e[4] = (__bf16)a3.x; af1.e[5] = (__bf16)a3.y;
            af1.e[6] = (__bf16)a3.z; af1.e[7] = (__bf16)a3.w;
        }

        // re-issue the freed slot for step+4 (WAR on pf[slot] orders after converts)
        if (step + 4 < 16) {
            const int mt2 = (step + 4) >> 2, s2 = (step + 4) & 3;
            const float* p = Abase + (long)mt2 * (16 * 4096) + koff[s2];
            pf[slot][0] = *(const float4*)(p);
            pf[slot][1] = *(const float4*)(p + 4);
            pf[slot][2] = *(const float4*)(p + 32);
            pf[slot][3] = *(const float4*)(p + 36);
        }

        // Hard scheduling fence: loads above may NOT sink below (keeps 3-4 load
        // groups in flight per wave); MFMA below may not hoist above.
        __builtin_amdgcn_sched_barrier(0);

        // 8 MFMAs for this (mt, s)
        const char* bbase = BtB + s * 8192;
        __builtin_amdgcn_s_setprio(1);
        #pragma unroll
        for (int kh = 0; kh < 2; ++kh) {
            const bf16x8 afv = kh ? af1.v : af0.v;
            const int kb = kh * 64 + (lane >> 4) * 16;
            #pragma unroll
            for (int n2 = 0; n2 < 4; ++n2) {
                const int nr = n2 * 16 + (lane & 15);
                bf16x8 bf = *(const bf16x8*)(bbase + nr * 128 + (kb ^ ((nr & 7) << 4)));
                acc[n2] = __builtin_amdgcn_mfma_f32_16x16x32_bf16(afv, bf, acc[n2], 0, 0, 0);
            }
        }
        __builtin_amdgcn_s_setprio(0);

        // C write at end of each m-tile (NT: keep A/B resident in caches)
        if (s == 3) {
            const long crow0 = mbase + mt * 16 + (lane >> 4) * 4;
            const long col0  = (long)c * 64 + (lane & 15);
            #pragma unroll
            for (int n2 = 0; n2 < 4; ++n2) {
                #pragma unroll
                for (int v = 0; v < 4; ++v)
                    __builtin_nontemporal_store(acc[n2][v],
                        &C[(crow0 + v) * 4096 + col0 + n2 * 16]);
                acc[n2] = f32x4{0.f, 0.f, 0.f, 0.f};
            }
        }
    }
}

extern "C" void kernel_launch(void* const* d_in, const int* in_sizes, int n_in,
                              void* d_out, int out_size, void* d_ws, size_t ws_size,
                              hipStream_t stream) {
    const float* A    = (const float*)d_in[0];
    const float* Bd   = (const float*)d_in[1];
    const int*   rowi = (const int*)d_in[2];
    const int*   di   = (const int*)d_in[3];
    float*       C    = (float*)d_out;

    dim3 grid(32 * 64);   // 32 m-chunks x 64 columns, m-chunk-major
    dim3 block(256);
    hipLaunchKernelGGL(sparse_linear_kernel, grid, block, 0, stream,
                       A, Bd, rowi, di, C);
}

// Round 9
// 58.449 us; speedup vs baseline: 1.2716x; 1.2716x over previous
//
#include <hip/hip_runtime.h>
#include <hip/hip_bf16.h>

typedef __bf16 bf16x8 __attribute__((ext_vector_type(8)));
typedef float  f32x4  __attribute__((ext_vector_type(4)));

// Async global->LDS DMA: no register result => the compiler cannot re-roll or
// sink this pipeline (rounds 4/6/7: every VGPR-carried pipeline was dissolved,
// VGPR 60/40/52, loads just-in-time, ~3.1 TB/s). Tracked by vmcnt.
__device__ __forceinline__ void dma16(const float* g, float* l) {
    typedef const __attribute__((address_space(1))) unsigned int* gp_t;
    typedef __attribute__((address_space(3))) unsigned int*       lp_t;
    __builtin_amdgcn_global_load_lds((gp_t)(const void*)g, (lp_t)(void*)l, 16, 0, 0);
}

// 256 threads = 4 waves; one column-block c, 256 M-rows (64/wave).
// B: 4 nonzero 64x64 blocks of col c staged ONCE to LDS (bf16 [s][n][k]
//    transposed, XOR-swizzled); fragments hoisted to regs once per s.
// A: per-WAVE private 3-slot LDS ring (4KB fp32/slot = one 16x64 step-tile),
//    filled by global_load_lds with pre-swizzled global source (linear dest;
//    read-side XOR r<<4 => 2-way bank aliasing, free). Wave-private => NO
//    barriers in the main loop; sync = counted s_waitcnt vmcnt(8) per step
//    (steady 12 DMAs outstanding; never 0 mid-loop). sched_barrier(0) after
//    each wait pins the per-step schedule (rule #18). C stores epilogue-only
//    so the vmcnt queue holds A-DMAs exclusively (counts exact).
__global__ __launch_bounds__(256, 2) void sparse_linear_kernel(
    const float* __restrict__ A, const float* __restrict__ Bd,
    const int* __restrict__ rowi, const int* __restrict__ di,
    float* __restrict__ C)
{
    __shared__ __align__(16) unsigned short Bt[4 * 64 * 64];   // 32 KB
    __shared__ __align__(16) float Aring[4][3][16 * 64];       // 48 KB: [wave][slot][16 rows x 64 k]
    char* BtB = (char*)Bt;

    const int bid = blockIdx.x;
    const int c   = bid & 63;          // m-chunk-major: A-panel sharers concurrent -> L2/L3 reuse
    const int mch = bid >> 6;          // 0..31
    const int t    = threadIdx.x;
    const int lane = t & 63;
    const int w    = t >> 6;           // 0..3

    int rs[4], ds[4];
    #pragma unroll
    for (int s = 0; s < 4; ++s) {
        rs[s] = rowi[s * 64 + c];
        ds[s] = di[s * 64 + c];
    }
    int koff[4];
    #pragma unroll
    for (int s = 0; s < 4; ++s) koff[s] = rs[s] * 64;

    const long mbase = (long)mch * 256 + w * 64;

    // ---- prologue: DMA-fill ring slots 0..2 = steps 0..2 (s=0; mt=0,1,2) ----
    // Instruction i covers tile rows i*4+(lane>>4); lane fetches the global
    // k-bytes that the swizzled read expects at its linear LDS position:
    // kbyte = ((lane&15)*16) ^ (rr<<4).
    #pragma unroll
    for (int st = 0; st < 3; ++st) {
        float* slotp = &Aring[w][st][0];
        #pragma unroll
        for (int i = 0; i < 4; ++i) {
            const int rr  = i * 4 + (lane >> 4);
            const int kfl = (((lane & 15) * 16) ^ (rr << 4)) >> 2;
            const float* g = A + (mbase + st * 16 + rr) * 4096 + koff[0] + kfl;
            dma16(g, slotp + i * 256);
        }
    }

    // ---- stage B once: wave sb stages block sb; lane n owns column n ----
    {
        const int n  = t & 63;
        const int sb = t >> 6;
        const float* Bg = Bd + (long)ds[sb] * 64 + n;   // row stride = BN*TB = 16384
        char* dst = BtB + sb * 8192 + n * 128;
        const int sw = (n & 7) << 4;
        #pragma unroll
        for (int k4 = 0; k4 < 16; ++k4) {
            union { ushort4 u; __bf16 e[4]; } pk;
            pk.e[0] = (__bf16)Bg[(long)(4 * k4 + 0) * 16384];
            pk.e[1] = (__bf16)Bg[(long)(4 * k4 + 1) * 16384];
            pk.e[2] = (__bf16)Bg[(long)(4 * k4 + 2) * 16384];
            pk.e[3] = (__bf16)Bg[(long)(4 * k4 + 3) * 16384];
            *(ushort4*)(dst + ((8 * k4) ^ sw)) = pk.u;
        }
    }
    __syncthreads();   // the only barrier (B visible to all waves)

    f32x4 acc[4][4];   // [mt][n2]; stores deferred to epilogue
    #pragma unroll
    for (int m = 0; m < 4; ++m)
        #pragma unroll
        for (int n2 = 0; n2 < 4; ++n2) acc[m][n2] = f32x4{0.f, 0.f, 0.f, 0.f};

    bf16x8 bfr[2][4];  // B fragments of current s, held 4 steps (read once per s)

    #pragma unroll
    for (int step = 0; step < 16; ++step) {
        const int s = step >> 2, mt = step & 3, slot = step % 3;

        // Counted wait: steady-state 12 DMAs outstanding; retire oldest 4
        // (this step's slot). Tail drains 8 -> 4 -> 0.
        if (step <= 13)      asm volatile("s_waitcnt vmcnt(8)" ::: "memory");
        else if (step == 14) asm volatile("s_waitcnt vmcnt(4)" ::: "memory");
        else                 asm volatile("s_waitcnt vmcnt(0)" ::: "memory");
        __builtin_amdgcn_sched_barrier(0);

        // B fragments: refresh once per s (register-held across 4 steps)
        if (mt == 0) {
            const char* bbase = BtB + s * 8192;
            #pragma unroll
            for (int kh = 0; kh < 2; ++kh)
                #pragma unroll
                for (int n2 = 0; n2 < 4; ++n2) {
                    const int nr = n2 * 16 + (lane & 15);
                    const int kb = kh * 64 + (lane >> 4) * 16;
                    bfr[kh][n2] = *(const bf16x8*)(bbase + nr * 128 + (kb ^ ((nr & 7) << 4)));
                }
        }

        // A fragment: swizzled read from ring slot; convert fp32->bf16
        const char* ab = (const char*)&Aring[w][slot][0];
        const int r   = lane & 15;
        const int q32 = (lane >> 4) * 32;
        f32x4 a0 = *(const f32x4*)(ab + r * 256 + ((q32)            ^ (r << 4)));
        f32x4 a1 = *(const f32x4*)(ab + r * 256 + ((q32 + 16)       ^ (r << 4)));
        f32x4 a2 = *(const f32x4*)(ab + r * 256 + ((128 + q32)      ^ (r << 4)));
        f32x4 a3 = *(const f32x4*)(ab + r * 256 + ((128 + q32 + 16) ^ (r << 4)));
        union { bf16x8 v; __bf16 e[8]; } af0, af1;
        #pragma unroll
        for (int i = 0; i < 4; ++i) {
            af0.e[i]     = (__bf16)a0[i];
            af0.e[i + 4] = (__bf16)a1[i];
            af1.e[i]     = (__bf16)a2[i];
            af1.e[i + 4] = (__bf16)a3[i];
        }

        // 8 MFMAs for this (s, mt)
        __builtin_amdgcn_s_setprio(1);
        #pragma unroll
        for (int kh = 0; kh < 2; ++kh) {
            const bf16x8 afv = kh ? af1.v : af0.v;
            #pragma unroll
            for (int n2 = 0; n2 < 4; ++n2)
                acc[mt][n2] = __builtin_amdgcn_mfma_f32_16x16x32_bf16(afv, bfr[kh][n2], acc[mt][n2], 0, 0, 0);
        }
        __builtin_amdgcn_s_setprio(0);

        // DMA-refill the just-consumed slot for step+3 (lands >=200cy later;
        // the slot's ds_reads above are long since complete).
        if (step + 3 < 16) {
            const int s2 = (step + 3) >> 2, mt2 = (step + 3) & 3;
            float* slotp = &Aring[w][slot][0];
            #pragma unroll
            for (int i = 0; i < 4; ++i) {
                const int rr  = i * 4 + (lane >> 4);
                const int kfl = (((lane & 15) * 16) ^ (rr << 4)) >> 2;
                const float* g = A + (mbase + mt2 * 16 + rr) * 4096 + koff[s2] + kfl;
                dma16(g, slotp + i * 256);
            }
        }
    }

    // ---- epilogue: all C stores (NT: keep A/B resident in caches) ----
    #pragma unroll
    for (int mt = 0; mt < 4; ++mt) {
        const long crow0 = mbase + mt * 16 + (lane >> 4) * 4;
        const long col0  = (long)c * 64 + (lane & 15);
        #pragma unroll
        for (int n2 = 0; n2 < 4; ++n2)
            #pragma unroll
            for (int v = 0; v < 4; ++v)
                __builtin_nontemporal_store(acc[mt][n2][v],
                    &C[(crow0 + v) * 4096 + col0 + n2 * 16]);
    }
}

extern "C" void kernel_launch(void* const* d_in, const int* in_sizes, int n_in,
                              void* d_out, int out_size, void* d_ws, size_t ws_size,
                              hipStream_t stream) {
    const float* A    = (const float*)d_in[0];
    const float* Bd   = (const float*)d_in[1];
    const int*   rowi = (const int*)d_in[2];
    const int*   di   = (const int*)d_in[3];
    float*       C    = (float*)d_out;

    dim3 grid(32 * 64);   // 32 m-chunks x 64 columns, m-chunk-major
    dim3 block(256);
    hipLaunchKernelGGL(sparse_linear_kernel, grid, block, 0, stream,
                       A, Bd, rowi, di, C);
}